// Round 2
// baseline (1301.174 us; speedup 1.0000x reference)
//
#include <hip/hip_runtime.h>
#include <math.h>

#define B_SZ 8
#define L_SEQ 4096
#define IN_DIM 256
#define D_MODEL 512
#define OUT_DIM 256
#define M_ROWS (B_SZ*L_SEQ)     // 32768
#define CH 64
#define NCH (L_SEQ/CH)          // 64

// d_out layout (floats): Re(x) [32768][512] at 0, y [32768][256] at Y_OFF
#define Y_OFF ((size_t)M_ROWS*D_MODEL)   // 16,777,216

// ws layout (floats), per-batch Xim to keep footprint ~11 MB
#define XIM_OFF 0                                  // [4096][512] one batch
#define WRE_OFF ((size_t)L_SEQ*D_MODEL)            // 2,097,152: [256][512]
#define WIM_OFF (WRE_OFF + (size_t)IN_DIM*D_MODEL) // [256][512]
#define CD_OFF  (WIM_OFF + (size_t)IN_DIM*D_MODEL) // [1280][256]
#define S_OFF   (CD_OFF + (size_t)1280*OUT_DIM)    // [64][512] float2 (one batch)

__global__ void build_w(const float* __restrict__ B_re, const float* __restrict__ B_im,
                        const float* __restrict__ gamma_log,
                        float* __restrict__ Wre, float* __restrict__ Wim) {
    int idx = blockIdx.x*256 + threadIdx.x;   // d*256 + h, 512*256 total
    int d = idx >> 8, h = idx & 255;
    float eg = expf(gamma_log[d]);
    Wre[h*512 + d] = B_re[idx]*eg;
    Wim[h*512 + d] = B_im[idx]*eg;
}

__global__ void build_c(const float* __restrict__ C_re, const float* __restrict__ C_im,
                        float* __restrict__ CD) {
    int idx = blockIdx.x*256 + threadIdx.x;   // n*512 + d, 256*512 total
    int d = idx & 511, n = idx >> 9;
    CD[(size_t)d*256 + n]       =  C_re[idx];
    CD[(size_t)(512+d)*256 + n] = -C_im[idx];
}

__global__ void build_d(const float* __restrict__ Dm, float* __restrict__ CD) {
    int idx = blockIdx.x*256 + threadIdx.x;   // n*256 + h, 256*256 total
    int n = idx >> 8, h = idx & 255;
    CD[(size_t)(1024+h)*256 + n] = Dm[idx];
}

// C[64x64 tile] = A[M x K] * B[K x N], row-major, dims multiples of 64/16
__global__ __launch_bounds__(256) void gemm64(const float* __restrict__ A, const float* __restrict__ Bm,
                                              float* __restrict__ C, int lda, int ldb, int ldc, int K) {
    __shared__ float As[16][65];
    __shared__ float Bs[16][68];
    const int tid = threadIdx.x;
    const int row0 = blockIdx.y*64, col0 = blockIdx.x*64;
    const int tx = tid & 15, ty = tid >> 4;
    const int ar = tid >> 2, ak = (tid & 3)*4;
    const int bk = tid >> 4, bn = (tid & 15)*4;
    float acc[4][4] = {};
    for (int k0 = 0; k0 < K; k0 += 16) {
        float4 av = *(const float4*)&A[(size_t)(row0+ar)*lda + k0 + ak];
        float4 bv = *(const float4*)&Bm[(size_t)(k0+bk)*ldb + col0 + bn];
        __syncthreads();
        As[ak+0][ar]=av.x; As[ak+1][ar]=av.y; As[ak+2][ar]=av.z; As[ak+3][ar]=av.w;
        *(float4*)&Bs[bk][bn] = bv;
        __syncthreads();
        #pragma unroll
        for (int kk = 0; kk < 16; ++kk) {
            float a[4], b[4];
            #pragma unroll
            for (int i = 0; i < 4; ++i) a[i] = As[kk][ty*4+i];
            #pragma unroll
            for (int j = 0; j < 4; ++j) b[j] = Bs[kk][tx*4+j];
            #pragma unroll
            for (int i = 0; i < 4; ++i)
                #pragma unroll
                for (int j = 0; j < 4; ++j) acc[i][j] += a[i]*b[j];
        }
    }
    #pragma unroll
    for (int i = 0; i < 4; ++i) {
        float4 v = make_float4(acc[i][0],acc[i][1],acc[i][2],acc[i][3]);
        *(float4*)&C[(size_t)(row0+ty*4+i)*ldc + col0 + tx*4] = v;
    }
}

// y[4096 x 256] = Xre*CD[0:512] + Xim*CD[512:1024] + inp*CD[1024:1280]
__global__ __launch_bounds__(256) void gemm_y(const float* __restrict__ Xre, const float* __restrict__ Xim,
                                              const float* __restrict__ inp, const float* __restrict__ Bm,
                                              float* __restrict__ C) {
    __shared__ float As[16][65];
    __shared__ float Bs[16][68];
    const int tid = threadIdx.x;
    const int row0 = blockIdx.y*64, col0 = blockIdx.x*64;
    const int tx = tid & 15, ty = tid >> 4;
    const int ar = tid >> 2, ak = (tid & 3)*4;
    const int bk = tid >> 4, bn = (tid & 15)*4;
    float acc[4][4] = {};
    for (int k0 = 0; k0 < 1280; k0 += 16) {
        const float* Asrc; int lda, kc;
        if      (k0 < 512)  { Asrc = Xre; lda = 512; kc = k0; }
        else if (k0 < 1024) { Asrc = Xim; lda = 512; kc = k0 - 512; }
        else                { Asrc = inp; lda = 256; kc = k0 - 1024; }
        float4 av = *(const float4*)&Asrc[(size_t)(row0+ar)*lda + kc + ak];
        float4 bv = *(const float4*)&Bm[(size_t)(k0+bk)*256 + col0 + bn];
        __syncthreads();
        As[ak+0][ar]=av.x; As[ak+1][ar]=av.y; As[ak+2][ar]=av.z; As[ak+3][ar]=av.w;
        *(float4*)&Bs[bk][bn] = bv;
        __syncthreads();
        #pragma unroll
        for (int kk = 0; kk < 16; ++kk) {
            float a[4], b[4];
            #pragma unroll
            for (int i = 0; i < 4; ++i) a[i] = As[kk][ty*4+i];
            #pragma unroll
            for (int j = 0; j < 4; ++j) b[j] = Bs[kk][tx*4+j];
            #pragma unroll
            for (int i = 0; i < 4; ++i)
                #pragma unroll
                for (int j = 0; j < 4; ++j) acc[i][j] += a[i]*b[j];
        }
    }
    #pragma unroll
    for (int i = 0; i < 4; ++i) {
        float4 v = make_float4(acc[i][0],acc[i][1],acc[i][2],acc[i][3]);
        *(float4*)&C[(size_t)(row0+ty*4+i)*256 + col0 + tx*4] = v;
    }
}

// phase 1: local chunk scans (zero carry), store end states; one batch
__global__ void scan_phase1(const float* __restrict__ xre, const float* __restrict__ xim,
                            const float* __restrict__ nu_log, const float* __restrict__ theta_log,
                            float* __restrict__ s) {
    int idx = blockIdx.x*256 + threadIdx.x;   // c*512 + d, NCH*D total
    int d = idx & (D_MODEL-1);
    int c = idx >> 9;
    float en = expf(nu_log[d]), et = expf(theta_log[d]);
    float mag = expf(-en);
    float ar = mag*cosf(et), ai = mag*sinf(et);
    float hr = 0.f, hi = 0.f;
    size_t off = (size_t)(c*CH)*D_MODEL + d;
    #pragma unroll 4
    for (int j = 0; j < CH; ++j) {
        float ur = xre[off], ui = xim[off];
        float nr = ar*hr - ai*hi + ur;
        float ni = ar*hi + ai*hr + ui;
        hr = nr; hi = ni;
        off += D_MODEL;
    }
    ((float2*)s)[idx] = make_float2(hr, hi);
}

// phase 2: serial scan of chunk end-states per d; overwrite s with carry-in
__global__ void scan_phase2(const float* __restrict__ nu_log, const float* __restrict__ theta_log,
                            float* __restrict__ s) {
    int d = blockIdx.x*256 + threadIdx.x;   // 512 total
    if (d >= D_MODEL) return;
    float en = expf(nu_log[d]), et = expf(theta_log[d]);
    float mag = expf(-(float)CH*en);
    float ang = (float)CH*et;
    float aCr = mag*cosf(ang), aCi = mag*sinf(ang);
    float er = 0.f, ei = 0.f;
    float2* sp = (float2*)s + d;
    for (int c = 0; c < NCH; ++c) {
        float2 v = sp[(size_t)c*D_MODEL];
        sp[(size_t)c*D_MODEL] = make_float2(er, ei);
        float nr = aCr*er - aCi*ei + v.x;
        float ni = aCr*ei + aCi*er + v.y;
        er = nr; ei = ni;
    }
}

// phase 3: redo local scans seeded with carry, write x re/im in place
__global__ void scan_phase3(float* __restrict__ xre, float* __restrict__ xim,
                            const float* __restrict__ nu_log, const float* __restrict__ theta_log,
                            const float* __restrict__ s) {
    int idx = blockIdx.x*256 + threadIdx.x;
    int d = idx & (D_MODEL-1);
    int c = idx >> 9;
    float en = expf(nu_log[d]), et = expf(theta_log[d]);
    float mag = expf(-en);
    float ar = mag*cosf(et), ai = mag*sinf(et);
    float2 carry = ((const float2*)s)[idx];
    float hr = carry.x, hi = carry.y;
    size_t off = (size_t)(c*CH)*D_MODEL + d;
    #pragma unroll 4
    for (int j = 0; j < CH; ++j) {
        float ur = xre[off], ui = xim[off];
        float nr = ar*hr - ai*hi + ur;
        float ni = ar*hi + ai*hr + ui;
        hr = nr; hi = ni;
        xre[off] = hr; xim[off] = hi;
        off += D_MODEL;
    }
}

extern "C" void kernel_launch(void* const* d_in, const int* in_sizes, int n_in,
                              void* d_out, int out_size, void* d_ws, size_t ws_size,
                              hipStream_t stream) {
    const float* inp       = (const float*)d_in[0];
    const float* nu_log    = (const float*)d_in[1];
    const float* theta_log = (const float*)d_in[2];
    const float* gamma_log = (const float*)d_in[3];
    const float* B_re      = (const float*)d_in[4];
    const float* B_im      = (const float*)d_in[5];
    const float* C_re      = (const float*)d_in[6];
    const float* C_im      = (const float*)d_in[7];
    const float* Dm        = (const float*)d_in[8];
    float* out = (float*)d_out;
    float* ws  = (float*)d_ws;
    float* Xim = ws + XIM_OFF;
    float* Wre = ws + WRE_OFF;
    float* Wim = ws + WIM_OFF;
    float* CD  = ws + CD_OFF;
    float* S   = ws + S_OFF;

    build_w<<<512, 256, 0, stream>>>(B_re, B_im, gamma_log, Wre, Wim);
    build_c<<<512, 256, 0, stream>>>(C_re, C_im, CD);
    build_d<<<256, 256, 0, stream>>>(Dm, CD);

    // u_re for all batches: [32768 x 256] x [256 x 512] -> d_out x-region
    dim3 gu(D_MODEL/64, M_ROWS/64);
    gemm64<<<gu, 256, 0, stream>>>(inp, Wre, out, IN_DIM, D_MODEL, D_MODEL, IN_DIM);

    for (int b = 0; b < B_SZ; ++b) {
        const float* inp_b = inp + (size_t)b*L_SEQ*IN_DIM;
        float* xre_b = out + (size_t)b*L_SEQ*D_MODEL;
        float* y_b   = out + Y_OFF + (size_t)b*L_SEQ*OUT_DIM;
        // u_im for batch b: [4096 x 256] x [256 x 512] -> ws.Xim
        dim3 gi(D_MODEL/64, L_SEQ/64);
        gemm64<<<gi, 256, 0, stream>>>(inp_b, Wim, Xim, IN_DIM, D_MODEL, D_MODEL, IN_DIM);
        // chunked scan on split planes
        scan_phase1<<<(NCH*D_MODEL)/256, 256, 0, stream>>>(xre_b, Xim, nu_log, theta_log, S);
        scan_phase2<<<2, 256, 0, stream>>>(nu_log, theta_log, S);
        scan_phase3<<<(NCH*D_MODEL)/256, 256, 0, stream>>>(xre_b, Xim, nu_log, theta_log, S);
        // y for batch b
        dim3 gy(OUT_DIM/64, L_SEQ/64);
        gemm_y<<<gy, 256, 0, stream>>>(xre_b, Xim, inp_b, CD, y_b);
    }
}

// Round 3
// 287.783 us; speedup vs baseline: 4.5214x; 4.5214x over previous
//
#include <hip/hip_runtime.h>
#include <math.h>

#define B_SZ 8
#define L_SEQ 4096
#define IN_DIM 256
#define D_MODEL 512
#define OUT_DIM 256
#define M_ROWS (B_SZ*L_SEQ)     // 32768
#define CH 64
#define NCH (L_SEQ/CH)          // 64

// d_out (floats): Re(x) [32768][512] at 0, y [32768][256] at Y_OFF
#define Y_OFF ((size_t)M_ROWS*D_MODEL)   // 16,777,216 floats

// ws byte offsets
#define XIM_B   ((size_t)0)                    // ushort [32768][512] = 33,554,432 B
#define WT_B    ((size_t)33554432)             // ushort [1024][256]  (B^T, rows 0..511=re, 512..1023=im)
#define CDT_B   ((size_t)34078720)             // ushort [256][1280]  (C_re | -C_im | D)
#define S_B     ((size_t)34734080)             // float2 [8][64][512] = 2 MB
// total ~36.8 MB

typedef __attribute__((ext_vector_type(8))) short short8;
typedef __attribute__((ext_vector_type(4))) float f32x4;
typedef unsigned short ushort_t;

__device__ __forceinline__ unsigned short f2b(float f) {
    unsigned u = __float_as_uint(f);
    unsigned r = u + 0x7FFF + ((u >> 16) & 1);   // RTNE
    return (unsigned short)(r >> 16);
}
__device__ __forceinline__ float b2f(unsigned short v) {
    return __uint_as_float((unsigned)v << 16);
}

__global__ void build_wt(const float* __restrict__ B_re, const float* __restrict__ B_im,
                         const float* __restrict__ gamma_log, ushort_t* __restrict__ Wt) {
    int idx = blockIdx.x*256 + threadIdx.x;    // 2*512*256 total
    int half = idx >> 17;                       // 0=re, 1=im
    int r = idx & 131071;
    int d = r >> 8;
    float eg = expf(gamma_log[d]);
    float v = (half ? B_im[r] : B_re[r]) * eg;
    Wt[(size_t)(half*512 + d)*256 + (r & 255)] = f2b(v);
}

__global__ void build_cdt(const float* __restrict__ C_re, const float* __restrict__ C_im,
                          const float* __restrict__ Dm, ushort_t* __restrict__ CDt) {
    int idx = blockIdx.x*256 + threadIdx.x;    // 256*1280 total
    int n = idx / 1280, k = idx % 1280;
    float v;
    if      (k < 512)  v =  C_re[n*512 + k];
    else if (k < 1024) v = -C_im[n*512 + (k-512)];
    else               v =  Dm[n*256 + (k-1024)];
    CDt[idx] = f2b(v);
}

// U = inp[32768x256] * Wt^T -> cols 0..511 fp32 to xre (d_out), cols 512..1023 bf16 to xim (ws)
__global__ __launch_bounds__(256) void gemm_u(const float* __restrict__ inp, const ushort_t* __restrict__ Wt,
                                              float* __restrict__ xre, ushort_t* __restrict__ xim) {
    __shared__ ushort_t Al[128][40];
    __shared__ ushort_t Bl[128][40];
    const int tid = threadIdx.x;
    const int wave = tid >> 6, lane = tid & 63;
    const int wr = wave >> 1, wc = wave & 1;
    const int fr = lane & 15, kg = lane >> 4;
    const int row0 = blockIdx.y*128, col0 = blockIdx.x*128;
    const int sr = tid >> 1, sh = (tid & 1)*16;
    f32x4 acc[4][4] = {};
    for (int k0 = 0; k0 < IN_DIM; k0 += 32) {
        const float* ap = inp + (size_t)(row0+sr)*IN_DIM + k0 + sh;
        float4 a0 = *(const float4*)(ap+0), a1 = *(const float4*)(ap+4);
        float4 a2 = *(const float4*)(ap+8), a3 = *(const float4*)(ap+12);
        const ushort_t* bp = Wt + (size_t)(col0+sr)*IN_DIM + k0 + sh;
        uint4 b0 = *(const uint4*)bp, b1 = *(const uint4*)(bp+8);
        ushort_t av[16];
        av[0]=f2b(a0.x); av[1]=f2b(a0.y); av[2]=f2b(a0.z); av[3]=f2b(a0.w);
        av[4]=f2b(a1.x); av[5]=f2b(a1.y); av[6]=f2b(a1.z); av[7]=f2b(a1.w);
        av[8]=f2b(a2.x); av[9]=f2b(a2.y); av[10]=f2b(a2.z); av[11]=f2b(a2.w);
        av[12]=f2b(a3.x); av[13]=f2b(a3.y); av[14]=f2b(a3.z); av[15]=f2b(a3.w);
        __syncthreads();
        *(uint4*)&Al[sr][sh]   = *(uint4*)&av[0];
        *(uint4*)&Al[sr][sh+8] = *(uint4*)&av[8];
        *(uint4*)&Bl[sr][sh]   = b0;
        *(uint4*)&Bl[sr][sh+8] = b1;
        __syncthreads();
        short8 af[4], bf[4];
        #pragma unroll
        for (int m = 0; m < 4; ++m) af[m] = *(const short8*)&Al[wr*64 + m*16 + fr][kg*8];
        #pragma unroll
        for (int n = 0; n < 4; ++n) bf[n] = *(const short8*)&Bl[wc*64 + n*16 + fr][kg*8];
        #pragma unroll
        for (int m = 0; m < 4; ++m)
            #pragma unroll
            for (int n = 0; n < 4; ++n)
                acc[m][n] = __builtin_amdgcn_mfma_f32_16x16x32_bf16(af[m], bf[n], acc[m][n], 0, 0, 0);
    }
    #pragma unroll
    for (int m = 0; m < 4; ++m)
        #pragma unroll
        for (int n = 0; n < 4; ++n) {
            int col = col0 + wc*64 + n*16 + fr;
            #pragma unroll
            for (int j = 0; j < 4; ++j) {
                int row = row0 + wr*64 + m*16 + kg*4 + j;
                if (col0 < 512) xre[(size_t)row*D_MODEL + col] = acc[m][n][j];
                else            xim[(size_t)row*D_MODEL + col - 512] = f2b(acc[m][n][j]);
            }
        }
}

// y[32768 x 256] = [xre | xim | inp] (K=1280) * CDt^T, fp32 out
__global__ __launch_bounds__(256) void gemm_y(const float* __restrict__ xre, const ushort_t* __restrict__ xim,
                                              const float* __restrict__ inp, const ushort_t* __restrict__ CDt,
                                              float* __restrict__ y) {
    __shared__ ushort_t Al[128][40];
    __shared__ ushort_t Bl[128][40];
    const int tid = threadIdx.x;
    const int wave = tid >> 6, lane = tid & 63;
    const int wr = wave >> 1, wc = wave & 1;
    const int fr = lane & 15, kg = lane >> 4;
    const int row0 = blockIdx.y*128, col0 = blockIdx.x*128;
    const int sr = tid >> 1, sh = (tid & 1)*16;
    f32x4 acc[4][4] = {};
    for (int k0 = 0; k0 < 1280; k0 += 32) {
        ushort_t av[16];
        if (k0 < 512) {
            const float* ap = xre + (size_t)(row0+sr)*D_MODEL + k0 + sh;
            #pragma unroll
            for (int i = 0; i < 16; i += 4) {
                float4 f = *(const float4*)(ap + i);
                av[i]=f2b(f.x); av[i+1]=f2b(f.y); av[i+2]=f2b(f.z); av[i+3]=f2b(f.w);
            }
        } else if (k0 < 1024) {
            const ushort_t* ap = xim + (size_t)(row0+sr)*D_MODEL + (k0-512) + sh;
            *(uint4*)&av[0] = *(const uint4*)ap;
            *(uint4*)&av[8] = *(const uint4*)(ap+8);
        } else {
            const float* ap = inp + (size_t)(row0+sr)*IN_DIM + (k0-1024) + sh;
            #pragma unroll
            for (int i = 0; i < 16; i += 4) {
                float4 f = *(const float4*)(ap + i);
                av[i]=f2b(f.x); av[i+1]=f2b(f.y); av[i+2]=f2b(f.z); av[i+3]=f2b(f.w);
            }
        }
        const ushort_t* bp = CDt + (size_t)(col0+sr)*1280 + k0 + sh;
        uint4 b0 = *(const uint4*)bp, b1 = *(const uint4*)(bp+8);
        __syncthreads();
        *(uint4*)&Al[sr][sh]   = *(uint4*)&av[0];
        *(uint4*)&Al[sr][sh+8] = *(uint4*)&av[8];
        *(uint4*)&Bl[sr][sh]   = b0;
        *(uint4*)&Bl[sr][sh+8] = b1;
        __syncthreads();
        short8 af[4], bf[4];
        #pragma unroll
        for (int m = 0; m < 4; ++m) af[m] = *(const short8*)&Al[wr*64 + m*16 + fr][kg*8];
        #pragma unroll
        for (int n = 0; n < 4; ++n) bf[n] = *(const short8*)&Bl[wc*64 + n*16 + fr][kg*8];
        #pragma unroll
        for (int m = 0; m < 4; ++m)
            #pragma unroll
            for (int n = 0; n < 4; ++n)
                acc[m][n] = __builtin_amdgcn_mfma_f32_16x16x32_bf16(af[m], bf[n], acc[m][n], 0, 0, 0);
    }
    #pragma unroll
    for (int m = 0; m < 4; ++m)
        #pragma unroll
        for (int n = 0; n < 4; ++n) {
            int col = col0 + wc*64 + n*16 + fr;
            #pragma unroll
            for (int j = 0; j < 4; ++j) {
                int row = row0 + wr*64 + m*16 + kg*4 + j;
                y[(size_t)row*OUT_DIM + col] = acc[m][n][j];
            }
        }
}

// phase 1: local chunk scans (zero carry), store end states (all batches)
__global__ void scan_phase1(const float* __restrict__ xre, const ushort_t* __restrict__ xim,
                            const float* __restrict__ nu_log, const float* __restrict__ theta_log,
                            float2* __restrict__ s) {
    int idx = blockIdx.x*256 + threadIdx.x;   // b*(NCH*D) + c*D + d
    int d = idx & (D_MODEL-1);
    int c = (idx >> 9) & (NCH-1);
    int b = idx >> 15;
    float en = expf(nu_log[d]), et = expf(theta_log[d]);
    float mag = expf(-en);
    float ar = mag*cosf(et), ai = mag*sinf(et);
    float hr = 0.f, hi = 0.f;
    size_t off = ((size_t)(b*L_SEQ) + c*CH)*D_MODEL + d;
    #pragma unroll 4
    for (int j = 0; j < CH; ++j) {
        float ur = xre[off], ui = b2f(xim[off]);
        float nr = ar*hr - ai*hi + ur;
        float ni = ar*hi + ai*hr + ui;
        hr = nr; hi = ni;
        off += D_MODEL;
    }
    s[idx] = make_float2(hr, hi);
}

// phase 2: serial scan of chunk end-states per (b,d); overwrite s with carry-in
__global__ void scan_phase2(const float* __restrict__ nu_log, const float* __restrict__ theta_log,
                            float2* __restrict__ s) {
    int idx = blockIdx.x*256 + threadIdx.x;   // b*D + d, 4096 total
    int d = idx & (D_MODEL-1);
    int b = idx >> 9;
    float en = expf(nu_log[d]), et = expf(theta_log[d]);
    float mag = expf(-(float)CH*en);
    float ang = (float)CH*et;
    float aCr = mag*cosf(ang), aCi = mag*sinf(ang);
    float er = 0.f, ei = 0.f;
    float2* sp = s + (size_t)b*NCH*D_MODEL + d;
    for (int c8 = 0; c8 < NCH; c8 += 8) {
        float2 v[8];
        #pragma unroll
        for (int i = 0; i < 8; ++i) v[i] = sp[(size_t)(c8+i)*D_MODEL];
        #pragma unroll
        for (int i = 0; i < 8; ++i) {
            sp[(size_t)(c8+i)*D_MODEL] = make_float2(er, ei);
            float nr = aCr*er - aCi*ei + v[i].x;
            float ni = aCr*ei + aCi*er + v[i].y;
            er = nr; ei = ni;
        }
    }
}

// phase 3: redo local scans seeded with carry; write x_re fp32, x_im bf16 in place
__global__ void scan_phase3(float* __restrict__ xre, ushort_t* __restrict__ xim,
                            const float* __restrict__ nu_log, const float* __restrict__ theta_log,
                            const float2* __restrict__ s) {
    int idx = blockIdx.x*256 + threadIdx.x;
    int d = idx & (D_MODEL-1);
    int c = (idx >> 9) & (NCH-1);
    int b = idx >> 15;
    float en = expf(nu_log[d]), et = expf(theta_log[d]);
    float mag = expf(-en);
    float ar = mag*cosf(et), ai = mag*sinf(et);
    float2 carry = s[idx];
    float hr = carry.x, hi = carry.y;
    size_t off = ((size_t)(b*L_SEQ) + c*CH)*D_MODEL + d;
    #pragma unroll 4
    for (int j = 0; j < CH; ++j) {
        float ur = xre[off], ui = b2f(xim[off]);
        float nr = ar*hr - ai*hi + ur;
        float ni = ar*hi + ai*hr + ui;
        hr = nr; hi = ni;
        xre[off] = hr; xim[off] = f2b(hi);
        off += D_MODEL;
    }
}

extern "C" void kernel_launch(void* const* d_in, const int* in_sizes, int n_in,
                              void* d_out, int out_size, void* d_ws, size_t ws_size,
                              hipStream_t stream) {
    const float* inp       = (const float*)d_in[0];
    const float* nu_log    = (const float*)d_in[1];
    const float* theta_log = (const float*)d_in[2];
    const float* gamma_log = (const float*)d_in[3];
    const float* B_re      = (const float*)d_in[4];
    const float* B_im      = (const float*)d_in[5];
    const float* C_re      = (const float*)d_in[6];
    const float* C_im      = (const float*)d_in[7];
    const float* Dm        = (const float*)d_in[8];
    float* out = (float*)d_out;
    char* wsb  = (char*)d_ws;
    ushort_t* Xim = (ushort_t*)(wsb + XIM_B);
    ushort_t* Wt  = (ushort_t*)(wsb + WT_B);
    ushort_t* CDt = (ushort_t*)(wsb + CDT_B);
    float2*   S   = (float2*)  (wsb + S_B);

    build_wt<<<1024, 256, 0, stream>>>(B_re, B_im, gamma_log, Wt);
    build_cdt<<<1280, 256, 0, stream>>>(C_re, C_im, Dm, CDt);

    dim3 gu(1024/128, M_ROWS/128);       // (8, 256)
    gemm_u<<<gu, 256, 0, stream>>>(inp, Wt, out, Xim);

    scan_phase1<<<(B_SZ*NCH*D_MODEL)/256, 256, 0, stream>>>(out, Xim, nu_log, theta_log, S);
    scan_phase2<<<(B_SZ*D_MODEL)/256, 256, 0, stream>>>(nu_log, theta_log, S);
    scan_phase3<<<(B_SZ*NCH*D_MODEL)/256, 256, 0, stream>>>(out, Xim, nu_log, theta_log, S);

    dim3 gy(OUT_DIM/128, M_ROWS/128);    // (2, 256)
    gemm_y<<<gy, 256, 0, stream>>>(out, Xim, inp, CDt, out + Y_OFF);
}

// Round 4
// 267.666 us; speedup vs baseline: 4.8612x; 1.0752x over previous
//
#include <hip/hip_runtime.h>
#include <hip/hip_bf16.h>
#include <math.h>

#define B_SZ 8
#define L_SEQ 4096
#define IN_DIM 256
#define D_MODEL 512
#define OUT_DIM 256
#define M_ROWS (B_SZ*L_SEQ)     // 32768
#define CH 64
#define NCH (L_SEQ/CH)          // 64

// d_out (floats): x-region [32768][512] at 0, y [32768][256] at Y_OFF.
// During gemm_u..phase3 the x-region holds interleaved bf16 (re,im) pairs
// [32768][1024] ushort; phase3 overwrites it in place with fp32 Re(x).
#define Y_OFF ((size_t)M_ROWS*D_MODEL)   // 16,777,216 floats

// ws byte offsets (total ~36.8 MB, proven to fit)
#define XIM_B   ((size_t)0)            // ushort [32768][512] = 33,554,432 B
#define WT_B    ((size_t)33554432)     // ushort [1024][256], row 2d=re, 2d+1=im
#define CDT_B   ((size_t)34078720)     // ushort [256][1280]  (C_re | -C_im | D)
#define S_B     ((size_t)34734080)     // float2 [8*64*512] = 2 MB

typedef __attribute__((ext_vector_type(8))) short short8;
typedef __attribute__((ext_vector_type(4))) float f32x4;
typedef unsigned short ushort_t;

__device__ __forceinline__ unsigned short f2b(float f) {
    unsigned u = __float_as_uint(f);
    unsigned r = u + 0x7FFF + ((u >> 16) & 1);   // RTNE
    return (unsigned short)(r >> 16);
}
__device__ __forceinline__ float b2f(unsigned v) {
    return __uint_as_float(v << 16);
}
__device__ __forceinline__ unsigned pk2(float lo, float hi) {
    __hip_bfloat162 h = __float22bfloat162_rn(make_float2(lo, hi));
    return *(unsigned*)&h;   // lo in low 16 bits
}

__global__ void build_wt(const float* __restrict__ B_re, const float* __restrict__ B_im,
                         const float* __restrict__ gamma_log, ushort_t* __restrict__ Wt) {
    int idx = blockIdx.x*256 + threadIdx.x;    // 1024*256 total
    int r = idx >> 8, h = idx & 255;
    int d = r >> 1, comp = r & 1;
    float eg = expf(gamma_log[d]);
    float v = (comp ? B_im[d*256 + h] : B_re[d*256 + h]) * eg;
    Wt[idx] = f2b(v);
}

__global__ void build_cdt(const float* __restrict__ C_re, const float* __restrict__ C_im,
                          const float* __restrict__ Dm, ushort_t* __restrict__ CDt) {
    int idx = blockIdx.x*256 + threadIdx.x;    // 256*1280 total
    int n = idx / 1280, k = idx % 1280;
    float v;
    if      (k < 512)  v =  C_re[n*512 + k];
    else if (k < 1024) v = -C_im[n*512 + (k-512)];
    else               v =  Dm[n*256 + (k-1024)];
    CDt[idx] = f2b(v);
}

// U = inp[32768x256] * Wt^T -> interleaved bf16 (re,im) pairs into d_out x-region
__global__ __launch_bounds__(256) void gemm_u(const float* __restrict__ inp, const ushort_t* __restrict__ Wt,
                                              ushort_t* __restrict__ xpair) {
    __shared__ ushort_t Al[128][40];
    __shared__ ushort_t Bl[128][40];
    const int tid = threadIdx.x;
    const int nwg = gridDim.x * gridDim.y;
    int orig = blockIdx.y * gridDim.x + blockIdx.x;
    int wg = (orig & 7) * (nwg >> 3) + (orig >> 3);
    const int row0 = (wg / gridDim.x) * 128, col0 = (wg % gridDim.x) * 128;
    const int wave = tid >> 6, lane = tid & 63;
    const int wr = wave >> 1, wc = wave & 1;
    const int fr = lane & 15, kg = lane >> 4;
    const int sr = tid >> 1, sh = (tid & 1)*16;
    f32x4 acc[4][4] = {};
    for (int k0 = 0; k0 < IN_DIM; k0 += 32) {
        const float* ap = inp + (size_t)(row0+sr)*IN_DIM + k0 + sh;
        float4 a0 = *(const float4*)(ap+0), a1 = *(const float4*)(ap+4);
        float4 a2 = *(const float4*)(ap+8), a3 = *(const float4*)(ap+12);
        const ushort_t* bp = Wt + (size_t)(col0+sr)*IN_DIM + k0 + sh;
        uint4 b0 = *(const uint4*)bp, b1 = *(const uint4*)(bp+8);
        unsigned av[8];
        av[0]=pk2(a0.x,a0.y); av[1]=pk2(a0.z,a0.w);
        av[2]=pk2(a1.x,a1.y); av[3]=pk2(a1.z,a1.w);
        av[4]=pk2(a2.x,a2.y); av[5]=pk2(a2.z,a2.w);
        av[6]=pk2(a3.x,a3.y); av[7]=pk2(a3.z,a3.w);
        __syncthreads();
        *(uint4*)&Al[sr][sh]   = *(uint4*)&av[0];
        *(uint4*)&Al[sr][sh+8] = *(uint4*)&av[4];
        *(uint4*)&Bl[sr][sh]   = b0;
        *(uint4*)&Bl[sr][sh+8] = b1;
        __syncthreads();
        short8 af[4], bf[4];
        #pragma unroll
        for (int m = 0; m < 4; ++m) af[m] = *(const short8*)&Al[wr*64 + m*16 + fr][kg*8];
        #pragma unroll
        for (int n = 0; n < 4; ++n) bf[n] = *(const short8*)&Bl[wc*64 + n*16 + fr][kg*8];
        #pragma unroll
        for (int m = 0; m < 4; ++m)
            #pragma unroll
            for (int n = 0; n < 4; ++n)
                acc[m][n] = __builtin_amdgcn_mfma_f32_16x16x32_bf16(af[m], bf[n], acc[m][n], 0, 0, 0);
    }
    #pragma unroll
    for (int m = 0; m < 4; ++m)
        #pragma unroll
        for (int n = 0; n < 4; ++n) {
            int col = col0 + wc*64 + n*16 + fr;
            #pragma unroll
            for (int j = 0; j < 4; ++j) {
                int row = row0 + wr*64 + m*16 + kg*4 + j;
                xpair[(size_t)row*1024 + col] = f2b(acc[m][n][j]);
            }
        }
}

// y[32768 x 256] = [xre(fp32,d_out) | xim(bf16,ws) | inp(fp32)] (K=1280) * CDt^T
__global__ __launch_bounds__(256) void gemm_y(const float* __restrict__ xre, const ushort_t* __restrict__ xim,
                                              const float* __restrict__ inp, const ushort_t* __restrict__ CDt,
                                              float* __restrict__ y) {
    __shared__ ushort_t Al[128][40];
    __shared__ ushort_t Bl[128][40];
    const int tid = threadIdx.x;
    const int nwg = gridDim.x * gridDim.y;
    int orig = blockIdx.y * gridDim.x + blockIdx.x;
    int wg = (orig & 7) * (nwg >> 3) + (orig >> 3);
    const int row0 = (wg / gridDim.x) * 128, col0 = (wg % gridDim.x) * 128;
    const int wave = tid >> 6, lane = tid & 63;
    const int wr = wave >> 1, wc = wave & 1;
    const int fr = lane & 15, kg = lane >> 4;
    const int sr = tid >> 1, sh = (tid & 1)*16;
    f32x4 acc[4][4] = {};
    for (int k0 = 0; k0 < 1280; k0 += 32) {
        unsigned av[8];
        if (k0 < 512) {
            const float* ap = xre + (size_t)(row0+sr)*D_MODEL + k0 + sh;
            #pragma unroll
            for (int i = 0; i < 4; ++i) {
                float4 f = *(const float4*)(ap + i*4);
                av[2*i]   = pk2(f.x, f.y);
                av[2*i+1] = pk2(f.z, f.w);
            }
        } else if (k0 < 1024) {
            const ushort_t* ap = xim + (size_t)(row0+sr)*D_MODEL + (k0-512) + sh;
            *(uint4*)&av[0] = *(const uint4*)ap;
            *(uint4*)&av[4] = *(const uint4*)(ap+8);
        } else {
            const float* ap = inp + (size_t)(row0+sr)*IN_DIM + (k0-1024) + sh;
            #pragma unroll
            for (int i = 0; i < 4; ++i) {
                float4 f = *(const float4*)(ap + i*4);
                av[2*i]   = pk2(f.x, f.y);
                av[2*i+1] = pk2(f.z, f.w);
            }
        }
        const ushort_t* bp = CDt + (size_t)(col0+sr)*1280 + k0 + sh;
        uint4 b0 = *(const uint4*)bp, b1 = *(const uint4*)(bp+8);
        __syncthreads();
        *(uint4*)&Al[sr][sh]   = *(uint4*)&av[0];
        *(uint4*)&Al[sr][sh+8] = *(uint4*)&av[4];
        *(uint4*)&Bl[sr][sh]   = b0;
        *(uint4*)&Bl[sr][sh+8] = b1;
        __syncthreads();
        short8 af[4], bf[4];
        #pragma unroll
        for (int m = 0; m < 4; ++m) af[m] = *(const short8*)&Al[wr*64 + m*16 + fr][kg*8];
        #pragma unroll
        for (int n = 0; n < 4; ++n) bf[n] = *(const short8*)&Bl[wc*64 + n*16 + fr][kg*8];
        #pragma unroll
        for (int m = 0; m < 4; ++m)
            #pragma unroll
            for (int n = 0; n < 4; ++n)
                acc[m][n] = __builtin_amdgcn_mfma_f32_16x16x32_bf16(af[m], bf[n], acc[m][n], 0, 0, 0);
    }
    #pragma unroll
    for (int m = 0; m < 4; ++m)
        #pragma unroll
        for (int n = 0; n < 4; ++n) {
            int col = col0 + wc*64 + n*16 + fr;
            #pragma unroll
            for (int j = 0; j < 4; ++j) {
                int row = row0 + wr*64 + m*16 + kg*4 + j;
                y[(size_t)row*OUT_DIM + col] = acc[m][n][j];
            }
        }
}

// phase 1: local chunk scans on interleaved pairs, store end states
__global__ void scan_phase1(const unsigned* __restrict__ xp,
                            const float* __restrict__ nu_log, const float* __restrict__ theta_log,
                            float2* __restrict__ s) {
    int idx = blockIdx.x*256 + threadIdx.x;   // b*(NCH*D) + c*D + d
    int d = idx & (D_MODEL-1);
    int c = (idx >> 9) & (NCH-1);
    int b = idx >> 15;
    float en = expf(nu_log[d]), et = expf(theta_log[d]);
    float mag = expf(-en);
    float ar = mag*cosf(et), ai = mag*sinf(et);
    float hr = 0.f, hi = 0.f;
    size_t off = ((size_t)(b*L_SEQ) + c*CH)*D_MODEL + d;
    #pragma unroll 4
    for (int j = 0; j < CH; ++j) {
        unsigned p = xp[off];
        float ur = b2f(p & 0xffffu), ui = b2f(p >> 16);
        float nr = ar*hr - ai*hi + ur;
        float ni = ar*hi + ai*hr + ui;
        hr = nr; hi = ni;
        off += D_MODEL;
    }
    s[idx] = make_float2(hr, hi);
}

// phase 2: serial scan of chunk end-states per (b,d); overwrite s with carry-in
__global__ void scan_phase2(const float* __restrict__ nu_log, const float* __restrict__ theta_log,
                            float2* __restrict__ s) {
    int idx = blockIdx.x*256 + threadIdx.x;   // b*D + d, 4096 total
    int d = idx & (D_MODEL-1);
    int b = idx >> 9;
    float en = expf(nu_log[d]), et = expf(theta_log[d]);
    float mag = expf(-(float)CH*en);
    float ang = (float)CH*et;
    float aCr = mag*cosf(ang), aCi = mag*sinf(ang);
    float er = 0.f, ei = 0.f;
    float2* sp = s + (size_t)b*NCH*D_MODEL + d;
    for (int c8 = 0; c8 < NCH; c8 += 8) {
        float2 v[8];
        #pragma unroll
        for (int i = 0; i < 8; ++i) v[i] = sp[(size_t)(c8+i)*D_MODEL];
        #pragma unroll
        for (int i = 0; i < 8; ++i) {
            sp[(size_t)(c8+i)*D_MODEL] = make_float2(er, ei);
            float nr = aCr*er - aCi*ei + v[i].x;
            float ni = aCr*ei + aCi*er + v[i].y;
            er = nr; ei = ni;
        }
    }
}

// phase 3: re-scan seeded with carry; overwrite pair with fp32 Re(x) in place,
// write Im(x) bf16 to ws for gemm_y
__global__ void scan_phase3(unsigned* __restrict__ xp, ushort_t* __restrict__ xim,
                            const float* __restrict__ nu_log, const float* __restrict__ theta_log,
                            const float2* __restrict__ s) {
    int idx = blockIdx.x*256 + threadIdx.x;
    int d = idx & (D_MODEL-1);
    int c = (idx >> 9) & (NCH-1);
    int b = idx >> 15;
    float en = expf(nu_log[d]), et = expf(theta_log[d]);
    float mag = expf(-en);
    float ar = mag*cosf(et), ai = mag*sinf(et);
    float2 carry = s[idx];
    float hr = carry.x, hi = carry.y;
    size_t off = ((size_t)(b*L_SEQ) + c*CH)*D_MODEL + d;
    #pragma unroll 4
    for (int j = 0; j < CH; ++j) {
        unsigned p = xp[off];
        float ur = b2f(p & 0xffffu), ui = b2f(p >> 16);
        float nr = ar*hr - ai*hi + ur;
        float ni = ar*hi + ai*hr + ui;
        hr = nr; hi = ni;
        xp[off] = __float_as_uint(hr);   // fp32 Re(x), same bytes
        xim[off] = f2b(hi);
        off += D_MODEL;
    }
}

extern "C" void kernel_launch(void* const* d_in, const int* in_sizes, int n_in,
                              void* d_out, int out_size, void* d_ws, size_t ws_size,
                              hipStream_t stream) {
    const float* inp       = (const float*)d_in[0];
    const float* nu_log    = (const float*)d_in[1];
    const float* theta_log = (const float*)d_in[2];
    const float* gamma_log = (const float*)d_in[3];
    const float* B_re      = (const float*)d_in[4];
    const float* B_im      = (const float*)d_in[5];
    const float* C_re      = (const float*)d_in[6];
    const float* C_im      = (const float*)d_in[7];
    const float* Dm        = (const float*)d_in[8];
    float* out = (float*)d_out;
    char* wsb  = (char*)d_ws;
    ushort_t* Xim = (ushort_t*)(wsb + XIM_B);
    ushort_t* Wt  = (ushort_t*)(wsb + WT_B);
    ushort_t* CDt = (ushort_t*)(wsb + CDT_B);
    float2*   S   = (float2*)  (wsb + S_B);

    build_wt<<<1024, 256, 0, stream>>>(B_re, B_im, gamma_log, Wt);
    build_cdt<<<1280, 256, 0, stream>>>(C_re, C_im, Dm, CDt);

    dim3 gu(1024/128, M_ROWS/128);       // (8, 256)
    gemm_u<<<gu, 256, 0, stream>>>(inp, Wt, (ushort_t*)out);

    scan_phase1<<<(B_SZ*NCH*D_MODEL)/256, 256, 0, stream>>>((const unsigned*)out, nu_log, theta_log, S);
    scan_phase2<<<(B_SZ*D_MODEL)/256, 256, 0, stream>>>(nu_log, theta_log, S);
    scan_phase3<<<(B_SZ*NCH*D_MODEL)/256, 256, 0, stream>>>((unsigned*)out, Xim, nu_log, theta_log, S);

    dim3 gy(OUT_DIM/128, M_ROWS/128);    // (2, 256)
    gemm_y<<<gy, 256, 0, stream>>>(out, Xim, inp, CDt, out + Y_OFF);
}

// Round 5
// 251.259 us; speedup vs baseline: 5.1786x; 1.0653x over previous
//
#include <hip/hip_runtime.h>
#include <hip/hip_bf16.h>
#include <math.h>

#define B_SZ 8
#define L_SEQ 4096
#define IN_DIM 256
#define D_MODEL 512
#define OUT_DIM 256
#define M_ROWS (B_SZ*L_SEQ)     // 32768
#define CH 64
#define NCH (L_SEQ/CH)          // 64

// d_out (floats): x-region [32768][512] at 0, y [32768][256] at Y_OFF.
// gemm_u writes interleaved bf16 (re,im) pairs [32768][1024] ushort into the
// x-region; phase3 overwrites it in place with fp32 Re(x).
#define Y_OFF ((size_t)M_ROWS*D_MODEL)   // 16,777,216 floats

// ws byte offsets (total ~53.6 MB)
#define XIM_B   ((size_t)0)            // ushort [32768][512] = 33,554,432 B
#define INPB_B  ((size_t)33554432)     // ushort [32768][256] = 16,777,216 B (inp bf16)
#define WT_B    ((size_t)50331648)     // ushort [1024][256], row 2d=re, 2d+1=im
#define CDT_B   ((size_t)50855936)     // ushort [256][1280]  (C_re | -C_im | D)
#define S_B     ((size_t)51511296)     // float2 [8*64*512] = 2 MB

typedef __attribute__((ext_vector_type(8))) short short8;
typedef __attribute__((ext_vector_type(4))) float f32x4;
typedef unsigned short ushort_t;
typedef unsigned int u32;

__device__ __forceinline__ unsigned short f2b(float f) {
    unsigned u = __float_as_uint(f);
    unsigned r = u + 0x7FFF + ((u >> 16) & 1);   // RTNE
    return (unsigned short)(r >> 16);
}
__device__ __forceinline__ float b2f(unsigned v) {
    return __uint_as_float(v << 16);
}
__device__ __forceinline__ unsigned pk2(float lo, float hi) {
    __hip_bfloat162 h = __float22bfloat162_rn(make_float2(lo, hi));
    return *(unsigned*)&h;   // lo in low 16 bits
}
__device__ __forceinline__ void async16(const void* g, void* l) {
    __builtin_amdgcn_global_load_lds((const __attribute__((address_space(1))) u32*)g,
                                     (__attribute__((address_space(3))) u32*)l, 16, 0, 0);
}

// inp fp32 -> bf16 (8 el/thread)
__global__ __launch_bounds__(256) void cvt_inp(const float* __restrict__ inp, ushort_t* __restrict__ inpb) {
    size_t i = ((size_t)blockIdx.x*256 + threadIdx.x)*8;
    float4 a = *(const float4*)(inp + i);
    float4 b = *(const float4*)(inp + i + 4);
    unsigned v[4] = { pk2(a.x,a.y), pk2(a.z,a.w), pk2(b.x,b.y), pk2(b.z,b.w) };
    *(uint4*)(inpb + i) = *(uint4*)v;
}

__global__ void build_wt(const float* __restrict__ B_re, const float* __restrict__ B_im,
                         const float* __restrict__ gamma_log, ushort_t* __restrict__ Wt) {
    int idx = blockIdx.x*256 + threadIdx.x;    // 1024*256 total
    int r = idx >> 8, h = idx & 255;
    int d = r >> 1, comp = r & 1;
    float eg = expf(gamma_log[d]);
    float v = (comp ? B_im[d*256 + h] : B_re[d*256 + h]) * eg;
    Wt[idx] = f2b(v);
}

__global__ void build_cdt(const float* __restrict__ C_re, const float* __restrict__ C_im,
                          const float* __restrict__ Dm, ushort_t* __restrict__ CDt) {
    int idx = blockIdx.x*256 + threadIdx.x;    // 256*1280 total
    int n = idx / 1280, k = idx % 1280;
    float v;
    if      (k < 512)  v =  C_re[n*512 + k];
    else if (k < 1024) v = -C_im[n*512 + (k-512)];
    else               v =  Dm[n*256 + (k-1024)];
    CDt[idx] = f2b(v);
}

// U = inp_bf16[32768x256] * Wt^T -> interleaved bf16 pairs into d_out x-region
// all-bf16, global_load_lds staging, BK=64
__global__ __launch_bounds__(256) void gemm_u(const ushort_t* __restrict__ inpb, const ushort_t* __restrict__ Wt,
                                              ushort_t* __restrict__ xpair) {
    __shared__ ushort_t Al[128*64];
    __shared__ ushort_t Bl[128*64];
    const int tid = threadIdx.x;
    int orig = blockIdx.x;
    int wg = (orig & 7) * 256 + (orig >> 3);   // nwg=2048, XCD-contiguous
    const int row0 = (wg >> 3) * 128, col0 = (wg & 7) * 128;
    const int wave = tid >> 6, lane = tid & 63;
    const int wr = wave >> 1, wc = wave & 1;
    const int fr = lane & 15, kg = lane >> 4;
    const int grow = tid >> 3, ggr = tid & 7;  // 32 rows per pass, 8 granules/row
    f32x4 acc[4][4] = {};
    for (int k0 = 0; k0 < IN_DIM; k0 += 64) {
        __syncthreads();
        #pragma unroll
        for (int i = 0; i < 4; ++i) {
            int row = grow + i*32;
            async16(inpb + (size_t)(row0+row)*IN_DIM + k0 + ggr*8, &Al[(row*8 + ggr)*8]);
        }
        #pragma unroll
        for (int i = 0; i < 4; ++i) {
            int row = grow + i*32;
            async16(Wt + (size_t)(col0+row)*IN_DIM + k0 + ggr*8, &Bl[(row*8 + ggr)*8]);
        }
        __syncthreads();
        #pragma unroll
        for (int kk = 0; kk < 2; ++kk) {
            short8 af[4], bf[4];
            #pragma unroll
            for (int m = 0; m < 4; ++m) af[m] = *(const short8*)&Al[(wr*64 + m*16 + fr)*64 + kk*32 + kg*8];
            #pragma unroll
            for (int n = 0; n < 4; ++n) bf[n] = *(const short8*)&Bl[(wc*64 + n*16 + fr)*64 + kk*32 + kg*8];
            #pragma unroll
            for (int m = 0; m < 4; ++m)
                #pragma unroll
                for (int n = 0; n < 4; ++n)
                    acc[m][n] = __builtin_amdgcn_mfma_f32_16x16x32_bf16(af[m], bf[n], acc[m][n], 0, 0, 0);
        }
    }
    #pragma unroll
    for (int m = 0; m < 4; ++m)
        #pragma unroll
        for (int n = 0; n < 4; ++n) {
            int col = col0 + wc*64 + n*16 + fr;
            #pragma unroll
            for (int j = 0; j < 4; ++j) {
                int row = row0 + wr*64 + m*16 + kg*4 + j;
                xpair[(size_t)row*1024 + col] = f2b(acc[m][n][j]);
            }
        }
}

// y = [xre(fp32) | xim(bf16) | inp_bf16] (K=1280) * CDt^T
__global__ __launch_bounds__(256) void gemm_y(const float* __restrict__ xre, const ushort_t* __restrict__ xim,
                                              const ushort_t* __restrict__ inpb, const ushort_t* __restrict__ CDt,
                                              float* __restrict__ y) {
    __shared__ ushort_t Al[128*64];
    __shared__ ushort_t Bl[128*64];
    const int tid = threadIdx.x;
    int orig = blockIdx.x;
    int wg = (orig & 7) * 64 + (orig >> 3);    // nwg=512
    const int row0 = (wg >> 1) * 128, col0 = (wg & 1) * 128;
    const int wave = tid >> 6, lane = tid & 63;
    const int wr = wave >> 1, wc = wave & 1;
    const int fr = lane & 15, kg = lane >> 4;
    const int grow = tid >> 3, ggr = tid & 7;
    const int crow = tid >> 1, csh = (tid & 1)*32;   // re-phase: row, 32-el half
    f32x4 acc[4][4] = {};
    for (int ks = 0; ks < 20; ++ks) {
        const int k0 = ks*64;
        __syncthreads();
        if (ks < 8) {
            // A: reg-stage fp32 -> bf16 -> LDS
            const float* ap = xre + (size_t)(row0+crow)*D_MODEL + k0 + csh;
            unsigned v[16];
            #pragma unroll
            for (int i = 0; i < 8; ++i) {
                float4 f = *(const float4*)(ap + i*4);
                v[2*i]   = pk2(f.x, f.y);
                v[2*i+1] = pk2(f.z, f.w);
            }
            // B staging via DMA
            #pragma unroll
            for (int i = 0; i < 4; ++i) {
                int row = grow + i*32;
                async16(CDt + (size_t)(col0+row)*1280 + k0 + ggr*8, &Bl[(row*8 + ggr)*8]);
            }
            ushort_t* dst = &Al[crow*64 + csh];
            #pragma unroll
            for (int i = 0; i < 4; ++i) *(uint4*)(dst + i*8) = *(uint4*)&v[i*4];
        } else {
            const ushort_t* asrc;
            size_t stride; int kc;
            if (ks < 16) { asrc = xim;  stride = D_MODEL; kc = k0 - 512; }
            else         { asrc = inpb; stride = IN_DIM;  kc = k0 - 1024; }
            #pragma unroll
            for (int i = 0; i < 4; ++i) {
                int row = grow + i*32;
                async16(asrc + (size_t)(row0+row)*stride + kc + ggr*8, &Al[(row*8 + ggr)*8]);
            }
            #pragma unroll
            for (int i = 0; i < 4; ++i) {
                int row = grow + i*32;
                async16(CDt + (size_t)(col0+row)*1280 + k0 + ggr*8, &Bl[(row*8 + ggr)*8]);
            }
        }
        __syncthreads();
        #pragma unroll
        for (int kk = 0; kk < 2; ++kk) {
            short8 af[4], bf[4];
            #pragma unroll
            for (int m = 0; m < 4; ++m) af[m] = *(const short8*)&Al[(wr*64 + m*16 + fr)*64 + kk*32 + kg*8];
            #pragma unroll
            for (int n = 0; n < 4; ++n) bf[n] = *(const short8*)&Bl[(wc*64 + n*16 + fr)*64 + kk*32 + kg*8];
            #pragma unroll
            for (int m = 0; m < 4; ++m)
                #pragma unroll
                for (int n = 0; n < 4; ++n)
                    acc[m][n] = __builtin_amdgcn_mfma_f32_16x16x32_bf16(af[m], bf[n], acc[m][n], 0, 0, 0);
        }
    }
    #pragma unroll
    for (int m = 0; m < 4; ++m)
        #pragma unroll
        for (int n = 0; n < 4; ++n) {
            int col = col0 + wc*64 + n*16 + fr;
            #pragma unroll
            for (int j = 0; j < 4; ++j) {
                int row = row0 + wr*64 + m*16 + kg*4 + j;
                y[(size_t)row*OUT_DIM + col] = acc[m][n][j];
            }
        }
}

// phase 1: local chunk scans on interleaved pairs, store end states
__global__ void scan_phase1(const unsigned* __restrict__ xp,
                            const float* __restrict__ nu_log, const float* __restrict__ theta_log,
                            float2* __restrict__ s) {
    int idx = blockIdx.x*256 + threadIdx.x;   // b*(NCH*D) + c*D + d
    int d = idx & (D_MODEL-1);
    int c = (idx >> 9) & (NCH-1);
    int b = idx >> 15;
    float en = expf(nu_log[d]), et = expf(theta_log[d]);
    float mag = expf(-en);
    float ar = mag*cosf(et), ai = mag*sinf(et);
    float hr = 0.f, hi = 0.f;
    size_t off = ((size_t)(b*L_SEQ) + c*CH)*D_MODEL + d;
    #pragma unroll 4
    for (int j = 0; j < CH; ++j) {
        unsigned p = xp[off];
        float ur = b2f(p & 0xffffu), ui = b2f(p >> 16);
        float nr = ar*hr - ai*hi + ur;
        float ni = ar*hi + ai*hr + ui;
        hr = nr; hi = ni;
        off += D_MODEL;
    }
    s[idx] = make_float2(hr, hi);
}

// phase 2: serial scan of chunk end-states per (b,d); overwrite s with carry-in
__global__ void scan_phase2(const float* __restrict__ nu_log, const float* __restrict__ theta_log,
                            float2* __restrict__ s) {
    int idx = blockIdx.x*256 + threadIdx.x;   // b*D + d, 4096 total
    int d = idx & (D_MODEL-1);
    int b = idx >> 9;
    float en = expf(nu_log[d]), et = expf(theta_log[d]);
    float mag = expf(-(float)CH*en);
    float ang = (float)CH*et;
    float aCr = mag*cosf(ang), aCi = mag*sinf(ang);
    float er = 0.f, ei = 0.f;
    float2* sp = s + (size_t)b*NCH*D_MODEL + d;
    for (int c8 = 0; c8 < NCH; c8 += 8) {
        float2 v[8];
        #pragma unroll
        for (int i = 0; i < 8; ++i) v[i] = sp[(size_t)(c8+i)*D_MODEL];
        #pragma unroll
        for (int i = 0; i < 8; ++i) {
            sp[(size_t)(c8+i)*D_MODEL] = make_float2(er, ei);
            float nr = aCr*er - aCi*ei + v[i].x;
            float ni = aCr*ei + aCi*er + v[i].y;
            er = nr; ei = ni;
        }
    }
}

// phase 3: re-scan seeded with carry; overwrite pair with fp32 Re(x) in place,
// write Im(x) bf16 to ws for gemm_y
__global__ void scan_phase3(unsigned* __restrict__ xp, ushort_t* __restrict__ xim,
                            const float* __restrict__ nu_log, const float* __restrict__ theta_log,
                            const float2* __restrict__ s) {
    int idx = blockIdx.x*256 + threadIdx.x;
    int d = idx & (D_MODEL-1);
    int c = (idx >> 9) & (NCH-1);
    int b = idx >> 15;
    float en = expf(nu_log[d]), et = expf(theta_log[d]);
    float mag = expf(-en);
    float ar = mag*cosf(et), ai = mag*sinf(et);
    float2 carry = s[idx];
    float hr = carry.x, hi = carry.y;
    size_t off = ((size_t)(b*L_SEQ) + c*CH)*D_MODEL + d;
    #pragma unroll 4
    for (int j = 0; j < CH; ++j) {
        unsigned p = xp[off];
        float ur = b2f(p & 0xffffu), ui = b2f(p >> 16);
        float nr = ar*hr - ai*hi + ur;
        float ni = ar*hi + ai*hr + ui;
        hr = nr; hi = ni;
        xp[off] = __float_as_uint(hr);   // fp32 Re(x), same bytes
        xim[off] = f2b(hi);
        off += D_MODEL;
    }
}

extern "C" void kernel_launch(void* const* d_in, const int* in_sizes, int n_in,
                              void* d_out, int out_size, void* d_ws, size_t ws_size,
                              hipStream_t stream) {
    const float* inp       = (const float*)d_in[0];
    const float* nu_log    = (const float*)d_in[1];
    const float* theta_log = (const float*)d_in[2];
    const float* gamma_log = (const float*)d_in[3];
    const float* B_re      = (const float*)d_in[4];
    const float* B_im      = (const float*)d_in[5];
    const float* C_re      = (const float*)d_in[6];
    const float* C_im      = (const float*)d_in[7];
    const float* Dm        = (const float*)d_in[8];
    float* out = (float*)d_out;
    char* wsb  = (char*)d_ws;
    ushort_t* Xim  = (ushort_t*)(wsb + XIM_B);
    ushort_t* Inpb = (ushort_t*)(wsb + INPB_B);
    ushort_t* Wt   = (ushort_t*)(wsb + WT_B);
    ushort_t* CDt  = (ushort_t*)(wsb + CDT_B);
    float2*   S    = (float2*)  (wsb + S_B);

    build_wt<<<1024, 256, 0, stream>>>(B_re, B_im, gamma_log, Wt);
    build_cdt<<<1280, 256, 0, stream>>>(C_re, C_im, Dm, CDt);
    cvt_inp<<<(M_ROWS*IN_DIM)/(256*8), 256, 0, stream>>>(inp, Inpb);

    gemm_u<<<2048, 256, 0, stream>>>(Inpb, Wt, (ushort_t*)out);

    scan_phase1<<<(B_SZ*NCH*D_MODEL)/256, 256, 0, stream>>>((const unsigned*)out, nu_log, theta_log, S);
    scan_phase2<<<(B_SZ*D_MODEL)/256, 256, 0, stream>>>(nu_log, theta_log, S);
    scan_phase3<<<(B_SZ*NCH*D_MODEL)/256, 256, 0, stream>>>((unsigned*)out, Xim, nu_log, theta_log, S);

    gemm_y<<<512, 256, 0, stream>>>(out, Xim, Inpb, CDt, out + Y_OFF);
}

// Round 7
// 244.577 us; speedup vs baseline: 5.3201x; 1.0273x over previous
//
#include <hip/hip_runtime.h>
#include <hip/hip_bf16.h>
#include <math.h>

#define B_SZ 8
#define L_SEQ 4096
#define IN_DIM 256
#define D_MODEL 512
#define OUT_DIM 256
#define M_ROWS (B_SZ*L_SEQ)     // 32768
#define CH 64
#define NCH (L_SEQ/CH)          // 64

// d_out (floats): fp32 Re(x) [32768][512] at 0 (written once by phase3),
// y [32768][256] at Y_OFF (written by gemm_y).
#define Y_OFF ((size_t)M_ROWS*D_MODEL)   // 16,777,216 floats

// ws byte offsets (~87 MB total)
#define XP_B    ((size_t)0)            // ushort [32768][1024] bf16 pairs (re,im) = 67,108,864 B
#define INPB_B  ((size_t)67108864)     // ushort [32768][256] inp bf16
#define WT_B    ((size_t)83886080)     // ushort [1024][256], row 2d=re, 2d+1=im
#define CDT_B   ((size_t)84410368)     // ushort [256][1280]: k<1024 interleaved C, then D
#define S_B     ((size_t)85065728)     // float2 [8*64*512] = 2 MB

typedef __attribute__((ext_vector_type(8))) short short8;
typedef __attribute__((ext_vector_type(4))) float f32x4;
typedef unsigned short ushort_t;
typedef unsigned int u32;

__device__ __forceinline__ unsigned short f2b(float f) {
    unsigned u = __float_as_uint(f);
    unsigned r = u + 0x7FFF + ((u >> 16) & 1);   // RTNE
    return (unsigned short)(r >> 16);
}
__device__ __forceinline__ float b2f(unsigned v) {
    return __uint_as_float(v << 16);
}
__device__ __forceinline__ unsigned pk2(float lo, float hi) {
    __hip_bfloat162 h = __float22bfloat162_rn(make_float2(lo, hi));
    return *(unsigned*)&h;   // lo in low 16 bits
}
__device__ __forceinline__ void async16(const void* g, void* l) {
    __builtin_amdgcn_global_load_lds((const __attribute__((address_space(1))) u32*)g,
                                     (__attribute__((address_space(3))) u32*)l, 16, 0, 0);
}

// inp fp32 -> bf16 (8 el/thread)
__global__ __launch_bounds__(256) void cvt_inp(const float* __restrict__ inp, ushort_t* __restrict__ inpb) {
    size_t i = ((size_t)blockIdx.x*256 + threadIdx.x)*8;
    float4 a = *(const float4*)(inp + i);
    float4 b = *(const float4*)(inp + i + 4);
    unsigned v[4] = { pk2(a.x,a.y), pk2(a.z,a.w), pk2(b.x,b.y), pk2(b.z,b.w) };
    *(uint4*)(inpb + i) = *(uint4*)v;
}

__global__ void build_wt(const float* __restrict__ B_re, const float* __restrict__ B_im,
                         const float* __restrict__ gamma_log, ushort_t* __restrict__ Wt) {
    int idx = blockIdx.x*256 + threadIdx.x;    // 1024*256 total
    int r = idx >> 8, h = idx & 255;
    int d = r >> 1, comp = r & 1;
    float eg = expf(gamma_log[d]);
    float v = (comp ? B_im[d*256 + h] : B_re[d*256 + h]) * eg;
    Wt[idx] = f2b(v);
}

__global__ void build_cdt(const float* __restrict__ C_re, const float* __restrict__ C_im,
                          const float* __restrict__ Dm, ushort_t* __restrict__ CDt) {
    int idx = blockIdx.x*256 + threadIdx.x;    // 256*1280 total
    int n = idx / 1280, k = idx % 1280;
    float v;
    if (k < 1024) {
        int d = k >> 1;
        v = (k & 1) ? -C_im[n*512 + d] : C_re[n*512 + d];
    } else {
        v = Dm[n*256 + (k-1024)];
    }
    CDt[idx] = f2b(v);
}

// U = inp_bf16[32768x256] * Wt^T -> bf16 pairs into ws.XP; LDS-staged epilogue
__global__ __launch_bounds__(256) void gemm_u(const ushort_t* __restrict__ inpb, const ushort_t* __restrict__ Wt,
                                              ushort_t* __restrict__ xpair) {
    __shared__ ushort_t lds[128*128];            // 32 KB: Al | Bl, reused by epilogue
    ushort_t* Al = lds;
    ushort_t* Bl = lds + 128*64;
    const int tid = threadIdx.x;
    int orig = blockIdx.x;
    int wg = (orig & 7) * 256 + (orig >> 3);     // nwg=2048, XCD-contiguous
    const int row0 = (wg >> 3) * 128, col0 = (wg & 7) * 128;
    const int wave = tid >> 6, lane = tid & 63;
    const int wr = wave >> 1, wc = wave & 1;
    const int fr = lane & 15, kg = lane >> 4;
    const int grow = tid >> 3, ggr = tid & 7;
    f32x4 acc[4][4] = {};
    for (int k0 = 0; k0 < IN_DIM; k0 += 64) {
        __syncthreads();
        #pragma unroll
        for (int i = 0; i < 4; ++i) {
            int row = grow + i*32;
            async16(inpb + (size_t)(row0+row)*IN_DIM + k0 + ggr*8, &Al[(row*8 + ggr)*8]);
        }
        #pragma unroll
        for (int i = 0; i < 4; ++i) {
            int row = grow + i*32;
            async16(Wt + (size_t)(col0+row)*IN_DIM + k0 + ggr*8, &Bl[(row*8 + ggr)*8]);
        }
        __syncthreads();
        #pragma unroll
        for (int kk = 0; kk < 2; ++kk) {
            short8 af[4], bf[4];
            #pragma unroll
            for (int m = 0; m < 4; ++m) af[m] = *(const short8*)&Al[(wr*64 + m*16 + fr)*64 + kk*32 + kg*8];
            #pragma unroll
            for (int n = 0; n < 4; ++n) bf[n] = *(const short8*)&Bl[(wc*64 + n*16 + fr)*64 + kk*32 + kg*8];
            #pragma unroll
            for (int m = 0; m < 4; ++m)
                #pragma unroll
                for (int n = 0; n < 4; ++n)
                    acc[m][n] = __builtin_amdgcn_mfma_f32_16x16x32_bf16(af[m], bf[n], acc[m][n], 0, 0, 0);
        }
    }
    // epilogue: acc -> swizzled LDS tile (bf16) -> coalesced 16B stores
    __syncthreads();
    #pragma unroll
    for (int m = 0; m < 4; ++m)
        #pragma unroll
        for (int n = 0; n < 4; ++n) {
            int colb = wc*64 + n*16 + fr;
            #pragma unroll
            for (int j = 0; j < 4; ++j) {
                int row = wr*64 + m*16 + kg*4 + j;
                int q = ((row >> 2) ^ row) & 3;
                lds[row*128 + (colb ^ (q << 4))] = f2b(acc[m][n][j]);
            }
        }
    __syncthreads();
    const int seg = tid & 15, rbase = tid >> 4;
    #pragma unroll
    for (int p = 0; p < 8; ++p) {
        int row = rbase + p*16;
        int q = ((row >> 2) ^ row) & 3;
        uint4 v = *(const uint4*)&lds[row*128 + ((seg*8) ^ (q << 4))];
        *(uint4*)&xpair[(size_t)(row0+row)*1024 + col0 + seg*8] = v;
    }
}

// y = [XP pairs | inp_bf16] (K=1280) * CDt^T, fp32 out; all-DMA staging
__global__ __launch_bounds__(256) void gemm_y(const ushort_t* __restrict__ xp,
                                              const ushort_t* __restrict__ inpb, const ushort_t* __restrict__ CDt,
                                              float* __restrict__ y) {
    __shared__ ushort_t lds[128*128];
    ushort_t* Al = lds;
    ushort_t* Bl = lds + 128*64;
    const int tid = threadIdx.x;
    int orig = blockIdx.x;
    int wg = (orig & 7) * 64 + (orig >> 3);      // nwg=512
    const int row0 = (wg >> 1) * 128, col0 = (wg & 1) * 128;
    const int wave = tid >> 6, lane = tid & 63;
    const int wr = wave >> 1, wc = wave & 1;
    const int fr = lane & 15, kg = lane >> 4;
    const int grow = tid >> 3, ggr = tid & 7;
    f32x4 acc[4][4] = {};
    for (int ks = 0; ks < 20; ++ks) {
        const int k0 = ks*64;
        __syncthreads();
        if (ks < 16) {
            #pragma unroll
            for (int i = 0; i < 4; ++i) {
                int row = grow + i*32;
                async16(xp + (size_t)(row0+row)*1024 + k0 + ggr*8, &Al[(row*8 + ggr)*8]);
            }
        } else {
            #pragma unroll
            for (int i = 0; i < 4; ++i) {
                int row = grow + i*32;
                async16(inpb + (size_t)(row0+row)*IN_DIM + (k0-1024) + ggr*8, &Al[(row*8 + ggr)*8]);
            }
        }
        #pragma unroll
        for (int i = 0; i < 4; ++i) {
            int row = grow + i*32;
            async16(CDt + (size_t)(col0+row)*1280 + k0 + ggr*8, &Bl[(row*8 + ggr)*8]);
        }
        __syncthreads();
        #pragma unroll
        for (int kk = 0; kk < 2; ++kk) {
            short8 af[4], bf[4];
            #pragma unroll
            for (int m = 0; m < 4; ++m) af[m] = *(const short8*)&Al[(wr*64 + m*16 + fr)*64 + kk*32 + kg*8];
            #pragma unroll
            for (int n = 0; n < 4; ++n) bf[n] = *(const short8*)&Bl[(wc*64 + n*16 + fr)*64 + kk*32 + kg*8];
            #pragma unroll
            for (int m = 0; m < 4; ++m)
                #pragma unroll
                for (int n = 0; n < 4; ++n)
                    acc[m][n] = __builtin_amdgcn_mfma_f32_16x16x32_bf16(af[m], bf[n], acc[m][n], 0, 0, 0);
        }
    }
    #pragma unroll
    for (int m = 0; m < 4; ++m)
        #pragma unroll
        for (int n = 0; n < 4; ++n) {
            int col = col0 + wc*64 + n*16 + fr;
            #pragma unroll
            for (int j = 0; j < 4; ++j) {
                int row = row0 + wr*64 + m*16 + kg*4 + j;
                y[(size_t)row*OUT_DIM + col] = acc[m][n][j];
            }
        }
}

// phase 1: local chunk scans on pairs, store end states
__global__ void scan_phase1(const unsigned* __restrict__ xp,
                            const float* __restrict__ nu_log, const float* __restrict__ theta_log,
                            float2* __restrict__ s) {
    int idx = blockIdx.x*256 + threadIdx.x;   // b*(NCH*D) + c*D + d
    int d = idx & (D_MODEL-1);
    int c = (idx >> 9) & (NCH-1);
    int b = idx >> 15;
    float en = expf(nu_log[d]), et = expf(theta_log[d]);
    float mag = expf(-en);
    float ar = mag*cosf(et), ai = mag*sinf(et);
    float hr = 0.f, hi = 0.f;
    size_t off = ((size_t)(b*L_SEQ) + c*CH)*D_MODEL + d;
    #pragma unroll 4
    for (int j = 0; j < CH; ++j) {
        unsigned p = xp[off];
        float ur = b2f(p & 0xffffu), ui = b2f(p >> 16);
        float nr = ar*hr - ai*hi + ur;
        float ni = ar*hi + ai*hr + ui;
        hr = nr; hi = ni;
        off += D_MODEL;
    }
    s[idx] = make_float2(hr, hi);
}

// phase 2: serial scan of chunk end-states per (b,d); overwrite s with carry-in
__global__ void scan_phase2(const float* __restrict__ nu_log, const float* __restrict__ theta_log,
                            float2* __restrict__ s) {
    int idx = blockIdx.x*256 + threadIdx.x;   // b*D + d, 4096 total
    int d = idx & (D_MODEL-1);
    int b = idx >> 9;
    float en = expf(nu_log[d]), et = expf(theta_log[d]);
    float mag = expf(-(float)CH*en);
    float ang = (float)CH*et;
    float aCr = mag*cosf(ang), aCi = mag*sinf(ang);
    float er = 0.f, ei = 0.f;
    float2* sp = s + (size_t)b*NCH*D_MODEL + d;
    for (int c8 = 0; c8 < NCH; c8 += 8) {
        float2 v[8];
        #pragma unroll
        for (int i = 0; i < 8; ++i) v[i] = sp[(size_t)(c8+i)*D_MODEL];
        #pragma unroll
        for (int i = 0; i < 8; ++i) {
            sp[(size_t)(c8+i)*D_MODEL] = make_float2(er, ei);
            float nr = aCr*er - aCi*ei + v[i].x;
            float ni = aCr*ei + aCi*er + v[i].y;
            er = nr; ei = ni;
        }
    }
}

// phase 3: re-scan with carry; write pairs (bf16) back to ws.XP for gemm_y
// AND fp32 Re(x) to d_out (final output)
__global__ void scan_phase3(unsigned* __restrict__ xp, float* __restrict__ xre_out,
                            const float* __restrict__ nu_log, const float* __restrict__ theta_log,
                            const float2* __restrict__ s) {
    int idx = blockIdx.x*256 + threadIdx.x;
    int d = idx & (D_MODEL-1);
    int c = (idx >> 9) & (NCH-1);
    int b = idx >> 15;
    float en = expf(nu_log[d]), et = expf(theta_log[d]);
    float mag = expf(-en);
    float ar = mag*cosf(et), ai = mag*sinf(et);
    float2 carry = s[idx];
    float hr = carry.x, hi = carry.y;
    size_t off = ((size_t)(b*L_SEQ) + c*CH)*D_MODEL + d;
    #pragma unroll 4
    for (int j = 0; j < CH; ++j) {
        unsigned p = xp[off];
        float ur = b2f(p & 0xffffu), ui = b2f(p >> 16);
        float nr = ar*hr - ai*hi + ur;
        float ni = ar*hi + ai*hr + ui;
        hr = nr; hi = ni;
        xp[off] = pk2(hr, hi);
        xre_out[off] = hr;
        off += D_MODEL;
    }
}

extern "C" void kernel_launch(void* const* d_in, const int* in_sizes, int n_in,
                              void* d_out, int out_size, void* d_ws, size_t ws_size,
                              hipStream_t stream) {
    const float* inp       = (const float*)d_in[0];
    const float* nu_log    = (const float*)d_in[1];
    const float* theta_log = (const float*)d_in[2];
    const float* gamma_log = (const float*)d_in[3];
    const float* B_re      = (const float*)d_in[4];
    const float* B_im      = (const float*)d_in[5];
    const float* C_re      = (const float*)d_in[6];
    const float* C_im      = (const float*)d_in[7];
    const float* Dm        = (const float*)d_in[8];
    float* out = (float*)d_out;
    char* wsb  = (char*)d_ws;
    ushort_t* XP   = (ushort_t*)(wsb + XP_B);
    ushort_t* Inpb = (ushort_t*)(wsb + INPB_B);
    ushort_t* Wt   = (ushort_t*)(wsb + WT_B);
    ushort_t* CDt  = (ushort_t*)(wsb + CDT_B);
    float2*   S    = (float2*)  (wsb + S_B);

    build_wt<<<1024, 256, 0, stream>>>(B_re, B_im, gamma_log, Wt);
    build_cdt<<<1280, 256, 0, stream>>>(C_re, C_im, Dm, CDt);
    cvt_inp<<<(M_ROWS*IN_DIM)/(256*8), 256, 0, stream>>>(inp, Inpb);

    gemm_u<<<2048, 256, 0, stream>>>(Inpb, Wt, XP);

    scan_phase1<<<(B_SZ*NCH*D_MODEL)/256, 256, 0, stream>>>((const unsigned*)XP, nu_log, theta_log, S);
    scan_phase2<<<(B_SZ*D_MODEL)/256, 256, 0, stream>>>(nu_log, theta_log, S);
    scan_phase3<<<(B_SZ*NCH*D_MODEL)/256, 256, 0, stream>>>((unsigned*)XP, out, nu_log, theta_log, S);

    gemm_y<<<512, 256, 0, stream>>>(XP, Inpb, CDt, out + Y_OFF);
}

// Round 12
// 242.493 us; speedup vs baseline: 5.3658x; 1.0086x over previous
//
#include <hip/hip_runtime.h>
#include <hip/hip_bf16.h>
#include <math.h>

#define B_SZ 8
#define L_SEQ 4096
#define IN_DIM 256
#define D_MODEL 512
#define OUT_DIM 256
#define M_ROWS (B_SZ*L_SEQ)     // 32768
#define CH 64
#define NCH (L_SEQ/CH)          // 64

// d_out (floats): fp32 Re(x) [32768][512] at 0 (written once by phase3),
// y [32768][256] at Y_OFF (written by gemm_y).
#define Y_OFF ((size_t)M_ROWS*D_MODEL)   // 16,777,216 floats

// ws byte offsets (~87 MB total)
#define XP_B    ((size_t)0)            // ushort [32768][1024] bf16 pairs (re,im)
#define INPB_B  ((size_t)67108864)     // ushort [32768][256] inp bf16
#define WT_B    ((size_t)83886080)     // ushort [1024][256], row 2d=re, 2d+1=im
#define CDT_B   ((size_t)84410368)     // ushort [256][1280]: k<1024 interleaved C, then D
#define S_B     ((size_t)85065728)     // float2 [8*64*512] = 2 MB

typedef __attribute__((ext_vector_type(8))) short short8;
typedef __attribute__((ext_vector_type(4))) float f32x4;
typedef unsigned short ushort_t;
typedef unsigned int u32;

__device__ __forceinline__ unsigned short f2b(float f) {
    unsigned u = __float_as_uint(f);
    unsigned r = u + 0x7FFF + ((u >> 16) & 1);   // RTNE
    return (unsigned short)(r >> 16);
}
__device__ __forceinline__ float b2f(unsigned v) {
    return __uint_as_float(v << 16);
}
__device__ __forceinline__ unsigned pk2(float lo, float hi) {
    __hip_bfloat162 h = __float22bfloat162_rn(make_float2(lo, hi));
    return *(unsigned*)&h;   // lo in low 16 bits
}
__device__ __forceinline__ void async16(const void* g, void* l) {
    __builtin_amdgcn_global_load_lds((const __attribute__((address_space(1))) u32*)g,
                                     (__attribute__((address_space(3))) u32*)l, 16, 0, 0);
}

// merged: cvt_inp (blocks 0..4095) | build_wt (4096..5119) | build_cdt (5120..6399)
__global__ __launch_bounds__(256) void prep(const float* __restrict__ inp, ushort_t* __restrict__ inpb,
                                            const float* __restrict__ B_re, const float* __restrict__ B_im,
                                            const float* __restrict__ gamma_log, ushort_t* __restrict__ Wt,
                                            const float* __restrict__ C_re, const float* __restrict__ C_im,
                                            const float* __restrict__ Dm, ushort_t* __restrict__ CDt) {
    int bx = blockIdx.x;
    if (bx < 4096) {
        size_t i = ((size_t)bx*256 + threadIdx.x)*8;
        float4 a = *(const float4*)(inp + i);
        float4 b = *(const float4*)(inp + i + 4);
        unsigned v[4] = { pk2(a.x,a.y), pk2(a.z,a.w), pk2(b.x,b.y), pk2(b.z,b.w) };
        *(uint4*)(inpb + i) = *(uint4*)v;
    } else if (bx < 5120) {
        int idx = (bx-4096)*256 + threadIdx.x;    // 1024*256 total
        int r = idx >> 8, h = idx & 255;
        int d = r >> 1, comp = r & 1;
        float eg = expf(gamma_log[d]);
        float v = (comp ? B_im[d*256 + h] : B_re[d*256 + h]) * eg;
        Wt[idx] = f2b(v);
    } else {
        int idx = (bx-5120)*256 + threadIdx.x;    // 256*1280 total
        int n = idx / 1280, k = idx % 1280;
        float v;
        if (k < 1024) {
            int d = k >> 1;
            v = (k & 1) ? -C_im[n*512 + d] : C_re[n*512 + d];
        } else {
            v = Dm[n*256 + (k-1024)];
        }
        CDt[idx] = f2b(v);
    }
}

// U = inp_bf16[32768x256] * Wt^T -> bf16 pairs into ws.XP; LDS-staged epilogue
__global__ __launch_bounds__(256) void gemm_u(const ushort_t* __restrict__ inpb, const ushort_t* __restrict__ Wt,
                                              ushort_t* __restrict__ xpair) {
    __shared__ ushort_t lds[128*128];            // 32 KB: Al | Bl, reused by epilogue
    ushort_t* Al = lds;
    ushort_t* Bl = lds + 128*64;
    const int tid = threadIdx.x;
    int orig = blockIdx.x;
    int wg = (orig & 7) * 256 + (orig >> 3);     // nwg=2048, XCD-contiguous
    const int row0 = (wg >> 3) * 128, col0 = (wg & 7) * 128;
    const int wave = tid >> 6, lane = tid & 63;
    const int wr = wave >> 1, wc = wave & 1;
    const int fr = lane & 15, kg = lane >> 4;
    const int grow = tid >> 3, ggr = tid & 7;
    f32x4 acc[4][4] = {};
    for (int k0 = 0; k0 < IN_DIM; k0 += 64) {
        __syncthreads();
        #pragma unroll
        for (int i = 0; i < 4; ++i) {
            int row = grow + i*32;
            async16(inpb + (size_t)(row0+row)*IN_DIM + k0 + ggr*8, &Al[(row*8 + ggr)*8]);
        }
        #pragma unroll
        for (int i = 0; i < 4; ++i) {
            int row = grow + i*32;
            async16(Wt + (size_t)(col0+row)*IN_DIM + k0 + ggr*8, &Bl[(row*8 + ggr)*8]);
        }
        __syncthreads();
        #pragma unroll
        for (int kk = 0; kk < 2; ++kk) {
            short8 af[4], bf[4];
            #pragma unroll
            for (int m = 0; m < 4; ++m) af[m] = *(const short8*)&Al[(wr*64 + m*16 + fr)*64 + kk*32 + kg*8];
            #pragma unroll
            for (int n = 0; n < 4; ++n) bf[n] = *(const short8*)&Bl[(wc*64 + n*16 + fr)*64 + kk*32 + kg*8];
            #pragma unroll
            for (int m = 0; m < 4; ++m)
                #pragma unroll
                for (int n = 0; n < 4; ++n)
                    acc[m][n] = __builtin_amdgcn_mfma_f32_16x16x32_bf16(af[m], bf[n], acc[m][n], 0, 0, 0);
        }
    }
    // epilogue: acc -> swizzled LDS tile (bf16) -> coalesced 16B stores
    __syncthreads();
    #pragma unroll
    for (int m = 0; m < 4; ++m)
        #pragma unroll
        for (int n = 0; n < 4; ++n) {
            int colb = wc*64 + n*16 + fr;
            #pragma unroll
            for (int j = 0; j < 4; ++j) {
                int row = wr*64 + m*16 + kg*4 + j;
                int q = ((row >> 2) ^ row) & 3;
                lds[row*128 + (colb ^ (q << 4))] = f2b(acc[m][n][j]);
            }
        }
    __syncthreads();
    const int seg = tid & 15, rbase = tid >> 4;
    #pragma unroll
    for (int p = 0; p < 8; ++p) {
        int row = rbase + p*16;
        int q = ((row >> 2) ^ row) & 3;
        uint4 v = *(const uint4*)&lds[row*128 + ((seg*8) ^ (q << 4))];
        *(uint4*)&xpair[(size_t)(row0+row)*1024 + col0 + seg*8] = v;
    }
}

// y = [XP pairs | inp_bf16] (K=1280) * CDt^T, fp32 out; all-DMA staging
__global__ __launch_bounds__(256) void gemm_y(const ushort_t* __restrict__ xp,
                                              const ushort_t* __restrict__ inpb, const ushort_t* __restrict__ CDt,
                                              float* __restrict__ y) {
    __shared__ ushort_t lds[128*128];
    ushort_t* Al = lds;
    ushort_t* Bl = lds + 128*64;
    const int tid = threadIdx.x;
    int orig = blockIdx.x;
    int wg = (orig & 7) * 64 + (orig >> 3);      // nwg=512
    const int row0 = (wg >> 1) * 128, col0 = (wg & 1) * 128;
    const int wave = tid >> 6, lane = tid & 63;
    const int wr = wave >> 1, wc = wave & 1;
    const int fr = lane & 15, kg = lane >> 4;
    const int grow = tid >> 3, ggr = tid & 7;
    f32x4 acc[4][4] = {};
    for (int ks = 0; ks < 20; ++ks) {
        const int k0 = ks*64;
        __syncthreads();
        if (ks < 16) {
            #pragma unroll
            for (int i = 0; i < 4; ++i) {
                int row = grow + i*32;
                async16(xp + (size_t)(row0+row)*1024 + k0 + ggr*8, &Al[(row*8 + ggr)*8]);
            }
        } else {
            #pragma unroll
            for (int i = 0; i < 4; ++i) {
                int row = grow + i*32;
                async16(inpb + (size_t)(row0+row)*IN_DIM + (k0-1024) + ggr*8, &Al[(row*8 + ggr)*8]);
            }
        }
        #pragma unroll
        for (int i = 0; i < 4; ++i) {
            int row = grow + i*32;
            async16(CDt + (size_t)(col0+row)*1280 + k0 + ggr*8, &Bl[(row*8 + ggr)*8]);
        }
        __syncthreads();
        #pragma unroll
        for (int kk = 0; kk < 2; ++kk) {
            short8 af[4], bf[4];
            #pragma unroll
            for (int m = 0; m < 4; ++m) af[m] = *(const short8*)&Al[(wr*64 + m*16 + fr)*64 + kk*32 + kg*8];
            #pragma unroll
            for (int n = 0; n < 4; ++n) bf[n] = *(const short8*)&Bl[(wc*64 + n*16 + fr)*64 + kk*32 + kg*8];
            #pragma unroll
            for (int m = 0; m < 4; ++m)
                #pragma unroll
                for (int n = 0; n < 4; ++n)
                    acc[m][n] = __builtin_amdgcn_mfma_f32_16x16x32_bf16(af[m], bf[n], acc[m][n], 0, 0, 0);
        }
    }
    #pragma unroll
    for (int m = 0; m < 4; ++m)
        #pragma unroll
        for (int n = 0; n < 4; ++n) {
            int col = col0 + wc*64 + n*16 + fr;
            #pragma unroll
            for (int j = 0; j < 4; ++j) {
                int row = row0 + wr*64 + m*16 + kg*4 + j;
                y[(size_t)row*OUT_DIM + col] = acc[m][n][j];
            }
        }
}

// phase 1: local chunk scans on pairs, store end states (standalone, round-7 exact)
__global__ void scan_phase1(const unsigned* __restrict__ xp,
                            const float* __restrict__ nu_log, const float* __restrict__ theta_log,
                            float2* __restrict__ s) {
    int idx = blockIdx.x*256 + threadIdx.x;   // b*(NCH*D) + c*D + d
    int d = idx & (D_MODEL-1);
    int c = (idx >> 9) & (NCH-1);
    int b = idx >> 15;
    float en = expf(nu_log[d]), et = expf(theta_log[d]);
    float mag = expf(-en);
    float ar = mag*cosf(et), ai = mag*sinf(et);
    float hr = 0.f, hi = 0.f;
    size_t off = ((size_t)(b*L_SEQ) + c*CH)*D_MODEL + d;
    #pragma unroll 4
    for (int j = 0; j < CH; ++j) {
        unsigned p = xp[off];
        float ur = b2f(p & 0xffffu), ui = b2f(p >> 16);
        float nr = ar*hr - ai*hi + ur;
        float ni = ar*hi + ai*hr + ui;
        hr = nr; hi = ni;
        off += D_MODEL;
    }
    s[idx] = make_float2(hr, hi);
}

// phase 2: serial scan of chunk end-states per (b,d); overwrite s with carry-in
__global__ void scan_phase2(const float* __restrict__ nu_log, const float* __restrict__ theta_log,
                            float2* __restrict__ s) {
    int idx = blockIdx.x*256 + threadIdx.x;   // b*D + d, 4096 total
    int d = idx & (D_MODEL-1);
    int b = idx >> 9;
    float en = expf(nu_log[d]), et = expf(theta_log[d]);
    float mag = expf(-(float)CH*en);
    float ang = (float)CH*et;
    float aCr = mag*cosf(ang), aCi = mag*sinf(ang);
    float er = 0.f, ei = 0.f;
    float2* sp = s + (size_t)b*NCH*D_MODEL + d;
    for (int c8 = 0; c8 < NCH; c8 += 8) {
        float2 v[8];
        #pragma unroll
        for (int i = 0; i < 8; ++i) v[i] = sp[(size_t)(c8+i)*D_MODEL];
        #pragma unroll
        for (int i = 0; i < 8; ++i) {
            sp[(size_t)(c8+i)*D_MODEL] = make_float2(er, ei);
            float nr = aCr*er - aCi*ei + v[i].x;
            float ni = aCr*ei + aCi*er + v[i].y;
            er = nr; ei = ni;
        }
    }
}

// phase 3: re-scan with carry, 2 channels/thread; write pairs back to ws.XP
// (uint2) AND fp32 Re(x) to d_out (float2)
__global__ void scan_phase3(unsigned* __restrict__ xp, float* __restrict__ xre_out,
                            const float* __restrict__ nu_log, const float* __restrict__ theta_log,
                            const float2* __restrict__ s) {
    int idx = blockIdx.x*256 + threadIdx.x;   // b*(NCH*256) + c*256 + d2, 131072 total
    int d2 = idx & 255;
    int c = (idx >> 8) & (NCH-1);
    int b = idx >> 14;
    int d0 = d2*2;
    float en0 = expf(nu_log[d0]),   et0 = expf(theta_log[d0]);
    float en1 = expf(nu_log[d0+1]), et1 = expf(theta_log[d0+1]);
    float mg0 = expf(-en0), mg1 = expf(-en1);
    float ar0 = mg0*cosf(et0), ai0 = mg0*sinf(et0);
    float ar1 = mg1*cosf(et1), ai1 = mg1*sinf(et1);
    float4 cr = *(const float4*)&s[(size_t)b*NCH*D_MODEL + (size_t)c*D_MODEL + d0];
    float hr0 = cr.x, hi0 = cr.y, hr1 = cr.z, hi1 = cr.w;
    size_t off = ((size_t)(b*L_SEQ) + c*CH)*D_MODEL + d0;   // u32-index into xp == float-index into xre_out
    #pragma unroll 4
    for (int j = 0; j < CH; ++j) {
        uint2 P = *(const uint2*)&xp[off];
        float ur0 = b2f(P.x & 0xffffu), ui0 = b2f(P.x >> 16);
        float ur1 = b2f(P.y & 0xffffu), ui1 = b2f(P.y >> 16);
        float nr0 = ar0*hr0 - ai0*hi0 + ur0;
        float ni0 = ar0*hi0 + ai0*hr0 + ui0;
        hr0 = nr0; hi0 = ni0;
        float nr1 = ar1*hr1 - ai1*hi1 + ur1;
        float ni1 = ar1*hi1 + ai1*hr1 + ui1;
        hr1 = nr1; hi1 = ni1;
        uint2 W = { pk2(hr0, hi0), pk2(hr1, hi1) };
        *(uint2*)&xp[off] = W;
        *(float2*)&xre_out[off] = make_float2(hr0, hr1);
        off += D_MODEL;
    }
}

extern "C" void kernel_launch(void* const* d_in, const int* in_sizes, int n_in,
                              void* d_out, int out_size, void* d_ws, size_t ws_size,
                              hipStream_t stream) {
    const float* inp       = (const float*)d_in[0];
    const float* nu_log    = (const float*)d_in[1];
    const float* theta_log = (const float*)d_in[2];
    const float* gamma_log = (const float*)d_in[3];
    const float* B_re      = (const float*)d_in[4];
    const float* B_im      = (const float*)d_in[5];
    const float* C_re      = (const float*)d_in[6];
    const float* C_im      = (const float*)d_in[7];
    const float* Dm        = (const float*)d_in[8];
    float* out = (float*)d_out;
    char* wsb  = (char*)d_ws;
    ushort_t* XP   = (ushort_t*)(wsb + XP_B);
    ushort_t* Inpb = (ushort_t*)(wsb + INPB_B);
    ushort_t* Wt   = (ushort_t*)(wsb + WT_B);
    ushort_t* CDt  = (ushort_t*)(wsb + CDT_B);
    float2*   S    = (float2*)  (wsb + S_B);

    prep<<<6400, 256, 0, stream>>>(inp, Inpb, B_re, B_im, gamma_log, Wt, C_re, C_im, Dm, CDt);

    gemm_u<<<2048, 256, 0, stream>>>(Inpb, Wt, XP);

    scan_phase1<<<(B_SZ*NCH*D_MODEL)/256, 256, 0, stream>>>((const unsigned*)XP, nu_log, theta_log, S);
    scan_phase2<<<(B_SZ*D_MODEL)/256, 256, 0, stream>>>(nu_log, theta_log, S);
    scan_phase3<<<(B_SZ*NCH*(D_MODEL/2))/256, 256, 0, stream>>>((unsigned*)XP, out, nu_log, theta_log, S);

    gemm_y<<<512, 256, 0, stream>>>(XP, Inpb, CDt, out + Y_OFF);
}